// Round 4
// baseline (20875.545 us; speedup 1.0000x reference)
//
#include <hip/hip_runtime.h>
#include <cmath>

#define LEAK 0.95f
#define ILEAK 0.05f

typedef float f4 __attribute__((ext_vector_type(4)));

// ---------------- Phase 1: u = x @ W_in^T (fp32 tiled GEMM) ----------------
__global__ __launch_bounds__(256) void resv_gemm_uin(
    const float* __restrict__ A, const float* __restrict__ Bm,
    float* __restrict__ C, int M, int N, int K)
{
    __shared__ float As[16][68];
    __shared__ float Bs[16][68];
    const int tid = threadIdx.x;
    const int m0 = blockIdx.y * 64;
    const int n0 = blockIdx.x * 64;
    const int lm = tid >> 2;
    const int lk = (tid & 3) * 4;
    const int ty = tid >> 4;
    const int tx = tid & 15;

    float acc[4][4];
#pragma unroll
    for (int i = 0; i < 4; ++i)
#pragma unroll
        for (int j = 0; j < 4; ++j) acc[i][j] = 0.f;

    const float* Aptr = A + (size_t)(m0 + lm) * K + lk;
    const float* Bptr = Bm + (size_t)(n0 + lm) * K + lk;

    for (int k0 = 0; k0 < K; k0 += 16) {
        float4 av = *(const float4*)(Aptr + k0);
        float4 bv = *(const float4*)(Bptr + k0);
        __syncthreads();
        As[lk + 0][lm] = av.x; As[lk + 1][lm] = av.y;
        As[lk + 2][lm] = av.z; As[lk + 3][lm] = av.w;
        Bs[lk + 0][lm] = bv.x; Bs[lk + 1][lm] = bv.y;
        Bs[lk + 2][lm] = bv.z; Bs[lk + 3][lm] = bv.w;
        __syncthreads();
#pragma unroll
        for (int kk = 0; kk < 16; ++kk) {
            float4 a = *(const float4*)(&As[kk][ty * 4]);
            float4 b = *(const float4*)(&Bs[kk][tx * 4]);
            acc[0][0] += a.x * b.x; acc[0][1] += a.x * b.y; acc[0][2] += a.x * b.z; acc[0][3] += a.x * b.w;
            acc[1][0] += a.y * b.x; acc[1][1] += a.y * b.y; acc[1][2] += a.y * b.z; acc[1][3] += a.y * b.w;
            acc[2][0] += a.z * b.x; acc[2][1] += a.z * b.y; acc[2][2] += a.z * b.z; acc[2][3] += a.z * b.w;
            acc[3][0] += a.w * b.x; acc[3][1] += a.w * b.y; acc[3][2] += a.w * b.z; acc[3][3] += a.w * b.w;
        }
    }
    float* Cp = C + (size_t)(m0 + ty * 4) * N + n0 + tx * 4;
#pragma unroll
    for (int i = 0; i < 4; ++i) {
        float4 v = make_float4(acc[i][0], acc[i][1], acc[i][2], acc[i][3]);
        *(float4*)(Cp + (size_t)i * N) = v;
    }
}

// ---------------- Phase 2: reservoir recurrence (agent-scope sync) --------
// 256 wgs, 96KB dummy dynamic LDS forces 1 wg/CU (co-residency proven r1/r2).
// group g = bid&7 owns batches 4g..4g+3; row-wg r = bid>>3 owns rows 32r..+31.
// W_res slice lives in REGISTERS (32 x f4 per lane). prev is staged
// [k][b]-interleaved in LDS; compute reads are 32-lane broadcasts (no bank
// conflicts). Cross-wg sync: per-wg monotone flag words, relaxed agent-scope
// atomic store/load only (round-2-proven coherence, no fences, no RMW chain).
__global__ __launch_bounds__(256, 1) void resv_recur(
    const float* __restrict__ Wres,   // [1024][1024]
    float* __restrict__ out,          // [32][2048][1024] (pre-filled with u)
    float* __restrict__ statesI,      // ws: [2 slots][8 groups][1024 k][4 b]
    unsigned* __restrict__ flags)     // ws: [8 groups][32 wg] (one 128B line/group)
{
    constexpr int H = 1024, S = 2048;
    extern __shared__ float sm[];
    float* prevI = sm;                 // 4096 floats (16 KB), [k][b]
    float* uL    = sm + 4096;          // 2048 floats (8 KB)
    float* red   = sm + 4096 + 2048;   // 512 floats (2 KB)

    const int tid = threadIdx.x;
    const int g  = blockIdx.x & 7;
    const int r  = blockIdx.x >> 3;
    const int h0 = r * 32;
    const int b0 = g * 4;

    const int w   = tid >> 6;          // wave = k-quarter
    const int l   = tid & 63;
    const int lh  = l >> 5;            // k-half within quarter
    const int row = l & 31;            // row within this wg's 32-row block
    const int K0  = w * 256 + lh * 128;  // this lane's k-base (covers K0..K0+127)

    // ---- one-time: W_res[h0+row][K0 .. K0+127] into 32 f4 registers ----
    f4 Wreg[32];
    {
        const f4* wsrc = (const f4*)(Wres + (size_t)(h0 + row) * H + K0);
#pragma unroll
        for (int i = 0; i < 32; ++i) Wreg[i] = wsrc[i];
    }

    const int fb  = tid >> 5;          // finish: batch (tid<128)
    const int frw = tid & 31;          // finish: row

    unsigned* flagLine = flags + g * 32;
    const f4* pI = (const f4*)prevI;   // pI[k] = prev[k][b0..b0+3]

    for (int t = 0; t < S; ++t) {
        // ---- stage u[t..t+15] (plain loads; independent of flags) ----
        if ((t & 15) == 0) {
            for (int c = tid; c < 512; c += 256) {
                int rw4 = c & 7, b = (c >> 3) & 3, tt = c >> 5;
                const float4* src =
                    (const float4*)(out + ((size_t)(b0 + b) * S + (t + tt)) * H + h0);
                ((float4*)uL)[(tt * 4 + b) * 8 + rw4] = src[rw4];
            }
        }
        // ---- wait for all 32 wgs of this group to publish states(t) ----
        if (t) {
            const unsigned tgt = (unsigned)t;
            unsigned fv;
            do {
                fv = __hip_atomic_load(flagLine + (tid & 31), __ATOMIC_RELAXED,
                                       __HIP_MEMORY_SCOPE_AGENT);
            } while (__any((int)(fv < tgt)));
            __builtin_amdgcn_sched_barrier(0);
        }
        // ---- stage prev (16 KB, [k][b]) via agent-scope atomic loads ----
        {
            const unsigned long long* src =
                (const unsigned long long*)(statesI + (size_t)((t & 1) * 8 + g) * 4096);
            unsigned long long* dst = (unsigned long long*)prevI;
#pragma unroll
            for (int c = 0; c < 8; ++c) {
                dst[tid + c * 256] = __hip_atomic_load(src + tid + c * 256,
                                                       __ATOMIC_RELAXED,
                                                       __HIP_MEMORY_SCOPE_AGENT);
            }
        }
        __syncthreads();

        // ---- compute: acc[b] = sum_k W[row][k] * prev[k][b] (broadcasts) ----
        f4 acc = (f4)(0.f);
#pragma unroll
        for (int i = 0; i < 32; ++i) {
            f4 P0 = pI[K0 + 4 * i + 0];
            f4 P1 = pI[K0 + 4 * i + 1];
            f4 P2 = pI[K0 + 4 * i + 2];
            f4 P3 = pI[K0 + 4 * i + 3];
            acc += Wreg[i].x * P0;
            acc += Wreg[i].y * P1;
            acc += Wreg[i].z * P2;
            acc += Wreg[i].w * P3;
        }
        // combine the two k-halves (lanes l and l^32 share a row)
        acc.x += __shfl_xor(acc.x, 32, 64);
        acc.y += __shfl_xor(acc.y, 32, 64);
        acc.z += __shfl_xor(acc.z, 32, 64);
        acc.w += __shfl_xor(acc.w, 32, 64);
        if (l < 32) ((f4*)red)[w * 32 + row] = acc;
        __syncthreads();

        // ---- finish: sum quarters, tanh, leak, publish ----
        if (tid < 128) {
            float sum = red[(0 * 32 + frw) * 4 + fb] + red[(1 * 32 + frw) * 4 + fb]
                      + red[(2 * 32 + frw) * 4 + fb] + red[(3 * 32 + frw) * 4 + fb];
            float uv = uL[(((t & 15) * 4 + fb) << 5) + frw];
            float pv = prevI[((h0 + frw) << 2) + fb];
            float ns = LEAK * tanhf(uv + sum) + ILEAK * pv;
            __hip_atomic_store(
                statesI + (size_t)(((t + 1) & 1) * 8 + g) * 4096 + ((h0 + frw) << 2) + fb,
                ns, __ATOMIC_RELAXED, __HIP_MEMORY_SCOPE_AGENT);
            out[((size_t)(b0 + fb) * S + t) * H + h0 + frw] = ns;
        }
        __syncthreads();   // entry drains each wave's vmcnt -> states at agent CP

        if (tid == 0 && t < S - 1) {
            __hip_atomic_store(flagLine + r, (unsigned)(t + 1), __ATOMIC_RELAXED,
                               __HIP_MEMORY_SCOPE_AGENT);
        }
    }
}

extern "C" void kernel_launch(void* const* d_in, const int* in_sizes, int n_in,
                              void* d_out, int out_size, void* d_ws, size_t ws_size,
                              hipStream_t stream)
{
    const float* x    = (const float*)d_in[0];   // [32][2048][512]
    const float* Win  = (const float*)d_in[1];   // [1024][512]
    const float* Wres = (const float*)d_in[2];   // [1024][1024]
    float* out = (float*)d_out;                  // [32][2048][1024]

    float*    statesI = (float*)d_ws;                          // 262144 B
    unsigned* flags   = (unsigned*)((char*)d_ws + 262144);     // 1024 B

    // zero states (t=0 prev) and flags every launch (graph-replay safe)
    hipMemsetAsync(d_ws, 0, 262144 + 1024, stream);

    // phase 1: u = x @ W_in^T into d_out
    dim3 gemm_grid(1024 / 64, 65536 / 64);
    resv_gemm_uin<<<gemm_grid, 256, 0, stream>>>(x, Win, out, 65536, 1024, 512);

    // phase 2: recurrence. 96KB dummy dynamic LDS forces exactly 1 wg/CU
    // (co-residency of all 256 wgs proven in rounds 1-2).
    constexpr int kLds = 96 * 1024;
    hipFuncSetAttribute((const void*)resv_recur,
                        hipFuncAttributeMaxDynamicSharedMemorySize, kLds);
    resv_recur<<<dim3(256), dim3(256), kLds, stream>>>(Wres, out, statesI, flags);
}